// Round 1
// baseline (142.983 us; speedup 1.0000x reference)
//
#include <hip/hip_runtime.h>
#include <math.h>

#ifndef M_PI
#define M_PI 3.14159265358979323846
#endif

// -----------------------------------------------------------------------------
// Kernel 1: scalar prologue (single block, 256 threads)
//   - mu_unit = mu / ||mu||            -> ws[0..P-1]
//   - kappa_pos = clip(softplus_b20(kappa), 1e-25)
//   - logC = logSA - log_kummer(0.5, P/2, kappa_pos)
//   ws[P]   = logC
//   ws[P+1] = kappa_pos
// -----------------------------------------------------------------------------
__global__ __launch_bounds__(256) void watson_scalar_kernel(
    const float* __restrict__ mu, const float* __restrict__ kappa,
    float* __restrict__ ws, int P, int maxIter) {
    const int t = threadIdx.x;

    __shared__ float  s_f[256];
    __shared__ double s_d[256];
    __shared__ double s_off[256];

    // ---- mu normalization ----
    float m = (t < P) ? mu[t] : 0.0f;
    s_f[t] = m * m;
    __syncthreads();
    for (int s = 128; s > 0; s >>= 1) {
        if (t < s) s_f[t] += s_f[t + s];
        __syncthreads();
    }
    const float norm = sqrtf(s_f[0]);
    if (t < P) ws[t] = m / norm;

    // ---- kappa_pos: softplus(beta=20, threshold=1), then clip ----
    const float k = kappa[0];
    float kp = (k * 20.0f > 1.0f) ? k : (log1pf(expf(20.0f * k)) / 20.0f);
    kp = fmaxf(kp, 1e-25f);
    const float logkap = logf(kp);

    const float c = 0.5f * (float)P;   // b parameter
    const float a = 0.5f;

    // ---- log-Kummer series: terms j = 1 .. maxIter-1 ----
    const int nTerms = maxIter - 1;              // 49999
    const int chunk  = (nTerms + 255) / 256;     // per-thread chunk
    const int j0 = 1 + t * chunk;
    const int j1 = min(j0 + chunk, maxIter);     // exclusive

    // pass 1: per-thread chunk sums
    double localSum = 0.0;
    for (int j = j0; j < j1; ++j) {
        const float jf = (float)j;
        const float term = logf((a + jf - 1.0f) / (jf * (c + jf - 1.0f))) + logkap;
        localSum += (double)term;
    }
    s_d[t] = localSum;
    __syncthreads();

    // exclusive scan of chunk sums (256 elements, serial on thread 0 is fine)
    if (t == 0) {
        double acc = 0.0;
        for (int i = 0; i < 256; ++i) { s_off[i] = acc; acc += s_d[i]; }
    }
    __syncthreads();
    const double off = s_off[t];

    // pass 2: running-prefix max
    double run = off;
    double lmax = -1.0e300;
    for (int j = j0; j < j1; ++j) {
        const float jf = (float)j;
        const float term = logf((a + jf - 1.0f) / (jf * (c + jf - 1.0f))) + logkap;
        run += (double)term;
        lmax = fmax(lmax, run);
    }
    s_d[t] = lmax;
    __syncthreads();
    for (int s = 128; s > 0; s >>= 1) {
        if (t < s) s_d[t] = fmax(s_d[t], s_d[t + s]);
        __syncthreads();
    }
    const double M = fmax(s_d[0], 0.0);  // include the prepended cs[0] = 0
    __syncthreads();

    // pass 3: sum of exp(prefix - M)
    run = off;
    double lsum = 0.0;
    for (int j = j0; j < j1; ++j) {
        const float jf = (float)j;
        const float term = logf((a + jf - 1.0f) / (jf * (c + jf - 1.0f))) + logkap;
        run += (double)term;
        lsum += exp(run - M);
    }
    s_d[t] = lsum;
    __syncthreads();
    for (int s = 128; s > 0; s >>= 1) {
        if (t < s) s_d[t] += s_d[t + s];
        __syncthreads();
    }

    if (t == 0) {
        const double total  = s_d[0] + exp(0.0 - M);   // prepended zero term
        const double logkum = M + log(total);
        const double logSA  = lgamma((double)c) - log(2.0) - (double)c * log(M_PI);
        ws[P]     = (float)(logSA - logkum);  // logC
        ws[P + 1] = kp;                       // kappa_pos
    }
}

// -----------------------------------------------------------------------------
// Kernel 2: one wave per row. 64 lanes x float4 = one 1KB row of X (P = 256).
//   out[i] = logC + kappa_pos * (X[i] . mu_unit)^2
// -----------------------------------------------------------------------------
__global__ __launch_bounds__(256) void watson_matvec_kernel(
    const float4* __restrict__ X4, const float* __restrict__ ws,
    float* __restrict__ out, int N) {
    const int lane  = threadIdx.x & 63;
    const int wid   = threadIdx.x >> 6;
    const int wavesPerBlock = blockDim.x >> 6;
    const int waveId = blockIdx.x * wavesPerBlock + wid;
    const int nWaves = gridDim.x * wavesPerBlock;

    // hoist mu fragment + scalars into registers (P/4 = 64 float4s -> 1/lane)
    const float4 m4   = ((const float4*)ws)[lane];
    const float  logC = ws[256];
    const float  kp   = ws[257];

    for (int row = waveId; row < N; row += nWaves) {
        const float4 x4 = X4[(size_t)row * 64 + lane];
        float d = x4.x * m4.x + x4.y * m4.y + x4.z * m4.z + x4.w * m4.w;
        #pragma unroll
        for (int o = 32; o > 0; o >>= 1) d += __shfl_xor(d, o);
        if (lane == 0) out[row] = logC + kp * d * d;
    }
}

extern "C" void kernel_launch(void* const* d_in, const int* in_sizes, int n_in,
                              void* d_out, int out_size, void* d_ws, size_t ws_size,
                              hipStream_t stream) {
    const float* X     = (const float*)d_in[0];
    const float* mu    = (const float*)d_in[1];
    const float* kappa = (const float*)d_in[2];
    float* out = (float*)d_out;
    float* ws  = (float*)d_ws;

    const int P = in_sizes[1];          // 256
    const int N = in_sizes[0] / P;      // 400000
    const int MAX_ITER = 50000;

    watson_scalar_kernel<<<1, 256, 0, stream>>>(mu, kappa, ws, P, MAX_ITER);

    const int blocks = 2048;            // 8192 waves, grid-stride over rows
    watson_matvec_kernel<<<blocks, 256, 0, stream>>>(
        (const float4*)X, ws, out, N);
}

// Round 2
// 99.917 us; speedup vs baseline: 1.4310x; 1.4310x over previous
//
#include <hip/hip_runtime.h>
#include <math.h>

#ifndef M_PI
#define M_PI 3.14159265358979323846
#endif

// Single fused kernel. P is fixed at 256 by the problem (one float4 per lane).
//
// Per-block prologue (cheap, redundant per block):
//   - every thread loads its mu float4 (raw)
//   - wave 0 reduces ||mu||^2
//   - thread 0: kappa_pos = clip(softplus_b20(kappa)), log-Kummer series with
//     early exit (terms are strictly decreasing for j>9; once run < M-45 the
//     remaining terms contribute exactly 0 at f32 precision), logC via lgamma.
// Main loop: one wave per row, grid-stride, 2-row unroll.
//   out[i] = logC + (kappa_pos/||mu||^2) * (X[i] . mu_raw)^2

__global__ __launch_bounds__(256) void watson_fused_kernel(
    const float4* __restrict__ X4, const float4* __restrict__ mu4,
    const float* __restrict__ kappa, float* __restrict__ out,
    int N, int P, int maxIter) {
    const int tid  = threadIdx.x;
    const int lane = tid & 63;
    const int wid  = tid >> 6;

    __shared__ float s_norm2, s_logC, s_kp;

    // ---- mu fragment: every lane holds its float4 of mu (raw) ----
    const float4 m4 = mu4[lane];

    // ---- wave 0: ||mu||^2 via shuffle reduce ----
    if (wid == 0) {
        float ss = m4.x * m4.x + m4.y * m4.y + m4.z * m4.z + m4.w * m4.w;
        #pragma unroll
        for (int o = 32; o > 0; o >>= 1) ss += __shfl_xor(ss, o);
        if (lane == 0) s_norm2 = ss;
    }

    // ---- thread 0: kappa_pos + log-Kummer (early-exit) + logC ----
    if (tid == 0) {
        const float k = kappa[0];
        float kpf = (k * 20.0f > 1.0f) ? k : (log1pf(expf(20.0f * k)) / 20.0f);
        kpf = fmaxf(kpf, 1e-25f);
        s_kp = kpf;

        const double kp     = (double)kpf;
        const double logkap = log(kp);
        const double a = 0.5;
        const double b = 0.5 * (double)P;

        // streaming logsumexp over [0, cs_1, cs_2, ...]
        double run = 0.0;   // current prefix
        double M   = 0.0;   // running max (includes prepended 0)
        double S   = 1.0;   // sum of exp(prefix - M), includes the 0 term
        for (int j = 1; j < maxIter; ++j) {
            const double jd   = (double)j;
            const double term = log((a + jd - 1.0) / (jd * (b + jd - 1.0))) + logkap;
            run += term;
            if (run > M) { S = S * exp(M - run) + 1.0; M = run; }
            else         { S += exp(run - M); }
            // terms strictly decrease for j>9; once negative and 45 nats below
            // the max, all remaining prefixes contribute 0 at f32 precision.
            if (j > 10 && term < 0.0 && run < M - 45.0) break;
        }
        const double logkum = M + log(S);
        const double logSA  = lgamma(b) - log(2.0) - b * log(M_PI);
        s_logC = (float)(logSA - logkum);
    }
    __syncthreads();

    const float logC   = s_logC;
    const float kscale = s_kp / s_norm2;   // folds mu normalization into scale

    // ---- matvec: one wave per row ----
    const int wavesPerBlock = blockDim.x >> 6;
    const int waveId = blockIdx.x * wavesPerBlock + wid;
    const int nWaves = gridDim.x * wavesPerBlock;

    int row = waveId;
    for (; row + nWaves < N; row += 2 * nWaves) {
        const float4 x0 = X4[(size_t)row * 64 + lane];
        const float4 x1 = X4[(size_t)(row + nWaves) * 64 + lane];
        float d0 = x0.x * m4.x + x0.y * m4.y + x0.z * m4.z + x0.w * m4.w;
        float d1 = x1.x * m4.x + x1.y * m4.y + x1.z * m4.z + x1.w * m4.w;
        #pragma unroll
        for (int o = 32; o > 0; o >>= 1) {
            d0 += __shfl_xor(d0, o);
            d1 += __shfl_xor(d1, o);
        }
        if (lane == 0) {
            out[row]          = logC + kscale * d0 * d0;
            out[row + nWaves] = logC + kscale * d1 * d1;
        }
    }
    if (row < N) {
        const float4 x0 = X4[(size_t)row * 64 + lane];
        float d0 = x0.x * m4.x + x0.y * m4.y + x0.z * m4.z + x0.w * m4.w;
        #pragma unroll
        for (int o = 32; o > 0; o >>= 1) d0 += __shfl_xor(d0, o);
        if (lane == 0) out[row] = logC + kscale * d0 * d0;
    }
}

extern "C" void kernel_launch(void* const* d_in, const int* in_sizes, int n_in,
                              void* d_out, int out_size, void* d_ws, size_t ws_size,
                              hipStream_t stream) {
    const float* X     = (const float*)d_in[0];
    const float* mu    = (const float*)d_in[1];
    const float* kappa = (const float*)d_in[2];
    float* out = (float*)d_out;

    const int P = in_sizes[1];          // 256
    const int N = in_sizes[0] / P;      // 400000
    const int MAX_ITER = 50000;

    const int blocks = 2048;            // 8 blocks/CU, 32 waves/CU
    watson_fused_kernel<<<blocks, 256, 0, stream>>>(
        (const float4*)X, (const float4*)mu, kappa, out, N, P, MAX_ITER);
}

// Round 4
// 68.496 us; speedup vs baseline: 2.0875x; 1.4587x over previous
//
#include <hip/hip_runtime.h>
#include <math.h>

#ifndef M_PI
#define M_PI 3.14159265358979323846
#endif

typedef float f32x4 __attribute__((ext_vector_type(4)));

// Fully fused Watson log-pdf kernel. P = 256 (one float4 per lane per row).
//
// Per-block prologue, ALL-FLOAT (hardware v_log_f32/v_exp_f32; serial chain
// < 1us, vs ~7us for a double version which stalls every block at the sync):
//   - kappa_pos = clip(softplus_b20(kappa), 1e-25)
//   - log-Kummer series with early exit (terms strictly decrease after j~10;
//     once run < M - 30 nats, remaining terms are invisible at f32 precision)
//   - logC = lgammaf(c) - log 2 - c log pi - logkum
//   - mu normalization folded into the scale: out = logC + (kp/||mu||^2) d_raw^2
//
// Main loop: one wave per 4 CONSECUTIVE rows (4KB contiguous), grid-stride.
// Combined 4-row butterfly reduction: 7 shuffles per 4 rows (vs 24 naive):
//   offset-32 swap merges row pairs (0,1) and (2,3); offset-16 swap merges the
//   pairs; 4 intra-16 steps finish. Group g in {0..3} (lanes 16g..16g+15) ends
//   owning row idx = ((g&1)<<1)|(g>>1); its lane 0 stores one dword -> the 4
//   stores per wave-iter are 4 consecutive dwords.

__global__ __launch_bounds__(256) void watson_fused_kernel(
    const f32x4* __restrict__ X4, const f32x4* __restrict__ mu4,
    const float* __restrict__ kappa, float* __restrict__ out,
    int N, int P, int maxIter) {
    const int tid  = threadIdx.x;
    const int lane = tid & 63;
    const int wid  = tid >> 6;

    __shared__ float s_norm2, s_logC, s_kp;

    // mu fragment: lane l holds mu[4l .. 4l+3] (raw, un-normalized)
    const f32x4 m4 = mu4[lane];

    // wave 0: ||mu||^2
    if (wid == 0) {
        float ss = m4.x * m4.x + m4.y * m4.y + m4.z * m4.z + m4.w * m4.w;
        #pragma unroll
        for (int o = 32; o > 0; o >>= 1) ss += __shfl_xor(ss, o);
        if (lane == 0) s_norm2 = ss;
    }

    // thread 0: scalar prologue in f32 (hardware transcendentals)
    if (tid == 0) {
        const float k = kappa[0];
        float kp = (k * 20.0f > 1.0f) ? k : (log1pf(expf(20.0f * k)) / 20.0f);
        kp = fmaxf(kp, 1e-25f);
        s_kp = kp;

        const float logkap = logf(kp);
        const float b = 0.5f * (float)P;     // c = p/2; a = 0.5

        float run = 0.0f;   // current prefix sum of terms
        float M   = 0.0f;   // running max (includes prepended 0 term)
        float S   = 1.0f;   // sum of exp(prefix - M), includes the 0 term
        for (int j = 1; j < maxIter; ++j) {
            const float jf = (float)j;
            const float term = logf((jf - 0.5f) / (jf * (b + jf - 1.0f))) + logkap;
            run += term;
            if (run > M) { S = S * expf(M - run) + 1.0f; M = run; }
            else         { S += expf(run - M); }
            if (j > 10 && term < 0.0f && run < M - 30.0f) break;
        }
        const float logkum = M + logf(S);
        const float logSA  = lgammaf(b) - logf(2.0f) - b * logf((float)M_PI);
        s_logC = logSA - logkum;
    }
    __syncthreads();

    const float logC   = s_logC;
    const float kscale = s_kp / s_norm2;

    const int wavesPerBlock = blockDim.x >> 6;
    const int waveId = blockIdx.x * wavesPerBlock + wid;
    const int nWaves = gridDim.x * wavesPerBlock;

    for (int base = waveId * 4; base < N; base += nWaves * 4) {
        if (base + 3 < N) {
            const f32x4 x0 = __builtin_nontemporal_load(&X4[(size_t)(base + 0) * 64 + lane]);
            const f32x4 x1 = __builtin_nontemporal_load(&X4[(size_t)(base + 1) * 64 + lane]);
            const f32x4 x2 = __builtin_nontemporal_load(&X4[(size_t)(base + 2) * 64 + lane]);
            const f32x4 x3 = __builtin_nontemporal_load(&X4[(size_t)(base + 3) * 64 + lane]);

            float d0 = x0.x * m4.x + x0.y * m4.y + x0.z * m4.z + x0.w * m4.w;
            float d1 = x1.x * m4.x + x1.y * m4.y + x1.z * m4.z + x1.w * m4.w;
            float d2 = x2.x * m4.x + x2.y * m4.y + x2.z * m4.z + x2.w * m4.w;
            float d3 = x3.x * m4.x + x3.y * m4.y + x3.z * m4.z + x3.w * m4.w;

            // combined 4-row butterfly: 7 shuffles total
            float a01 = (lane < 32) ? d0 : d1;
            float b01 = (lane < 32) ? d1 : d0;
            a01 += __shfl_xor(b01, 32);          // rows 0(low)/1(high), 32-pair sums
            float a23 = (lane < 32) ? d2 : d3;
            float b23 = (lane < 32) ? d3 : d2;
            a23 += __shfl_xor(b23, 32);          // rows 2(low)/3(high)

            float f  = (lane & 16) ? a23 : a01;
            float fp = (lane & 16) ? a01 : a23;
            f += __shfl_xor(fp, 16);             // each 16-group owns one row

            f += __shfl_xor(f, 8);
            f += __shfl_xor(f, 4);
            f += __shfl_xor(f, 2);
            f += __shfl_xor(f, 1);

            if ((lane & 15) == 0) {
                const int g   = lane >> 4;
                const int idx = ((g & 1) << 1) | (g >> 1);  // 0,2,1,3
                out[base + idx] = logC + kscale * f * f;
            }
        } else {
            // generic tail (unused when N % 4 == 0)
            for (int r = base; r < N; ++r) {
                const f32x4 x0 = X4[(size_t)r * 64 + lane];
                float d0 = x0.x * m4.x + x0.y * m4.y + x0.z * m4.z + x0.w * m4.w;
                #pragma unroll
                for (int o = 32; o > 0; o >>= 1) d0 += __shfl_xor(d0, o);
                if (lane == 0) out[r] = logC + kscale * d0 * d0;
            }
        }
    }
}

extern "C" void kernel_launch(void* const* d_in, const int* in_sizes, int n_in,
                              void* d_out, int out_size, void* d_ws, size_t ws_size,
                              hipStream_t stream) {
    const float* X     = (const float*)d_in[0];
    const float* mu    = (const float*)d_in[1];
    const float* kappa = (const float*)d_in[2];
    float* out = (float*)d_out;

    const int P = in_sizes[1];          // 256
    const int N = in_sizes[0] / P;      // 400000
    const int MAX_ITER = 50000;

    const int blocks = 2048;            // 8 blocks/CU, 32 waves/CU
    watson_fused_kernel<<<blocks, 256, 0, stream>>>(
        (const f32x4*)X, (const f32x4*)mu, kappa, out, N, P, MAX_ITER);
}

// Round 5
// 67.485 us; speedup vs baseline: 2.1188x; 1.0150x over previous
//
#include <hip/hip_runtime.h>
#include <math.h>

#ifndef M_PI
#define M_PI 3.14159265358979323846
#endif

typedef float f32x4 __attribute__((ext_vector_type(4)));

// Fully fused Watson log-pdf kernel. P = 256 (one float4 per lane per row).
//
// Prologue (per-block, all-f32 hardware transcendentals, <1us):
//   kappa_pos = clip(softplus_b20(kappa)); log-Kummer with early exit
//   (terms strictly decrease after j~10; once run < M-30 nats the remaining
//   prefixes are invisible at f32); logC via lgammaf; mu-normalization folded
//   into the scale:  out = logC + (kp/||mu||^2) * (X . mu_raw)^2.
//
// Main loop: one wave per 8 CONSECUTIVE rows (8KB contiguous burst, 8 loads
// in flight per wave), grid-stride. Combined 8-row butterfly: 10 shuffles
// per 8 rows (vs 24*2=48 naive):
//   4x offset-32 swaps merge row pairs (0,1)(2,3)(4,5)(6,7)
//   2x offset-16 swaps -> 16-lane groups own one row of each quad
//   1x offset-8 swap   -> 8-lane groups own one row each
//   3 intra-8 steps (offsets 4,2,1) finish.
// 8-group h = lane>>3 ends owning row idx = ((h&1)<<2)|(((h>>1)&1)<<1)|(h>>2);
// its lane (lane&7)==0 stores one dword -> 8 consecutive dwords per iter.

__global__ __launch_bounds__(256) void watson_fused_kernel(
    const f32x4* __restrict__ X4, const f32x4* __restrict__ mu4,
    const float* __restrict__ kappa, float* __restrict__ out,
    int N, int P, int maxIter) {
    const int tid  = threadIdx.x;
    const int lane = tid & 63;
    const int wid  = tid >> 6;

    __shared__ float s_norm2, s_logC, s_kp;

    // mu fragment: lane l holds mu[4l .. 4l+3] (raw, un-normalized)
    const f32x4 m4 = mu4[lane];

    // wave 0: ||mu||^2
    if (wid == 0) {
        float ss = m4.x * m4.x + m4.y * m4.y + m4.z * m4.z + m4.w * m4.w;
        #pragma unroll
        for (int o = 32; o > 0; o >>= 1) ss += __shfl_xor(ss, o);
        if (lane == 0) s_norm2 = ss;
    }

    // thread 0: scalar prologue in f32 (hardware transcendentals)
    if (tid == 0) {
        const float k = kappa[0];
        float kp = (k * 20.0f > 1.0f) ? k : (log1pf(expf(20.0f * k)) / 20.0f);
        kp = fmaxf(kp, 1e-25f);
        s_kp = kp;

        const float logkap = logf(kp);
        const float b = 0.5f * (float)P;     // c = p/2; a = 0.5

        float run = 0.0f;   // current prefix sum of terms
        float M   = 0.0f;   // running max (includes prepended 0 term)
        float S   = 1.0f;   // sum of exp(prefix - M), includes the 0 term
        for (int j = 1; j < maxIter; ++j) {
            const float jf = (float)j;
            const float term = logf((jf - 0.5f) / (jf * (b + jf - 1.0f))) + logkap;
            run += term;
            if (run > M) { S = S * expf(M - run) + 1.0f; M = run; }
            else         { S += expf(run - M); }
            if (j > 10 && term < 0.0f && run < M - 30.0f) break;
        }
        const float logkum = M + logf(S);
        const float logSA  = lgammaf(b) - logf(2.0f) - b * logf((float)M_PI);
        s_logC = logSA - logkum;
    }
    __syncthreads();

    const float logC   = s_logC;
    const float kscale = s_kp / s_norm2;

    const int wavesPerBlock = blockDim.x >> 6;
    const int waveId = blockIdx.x * wavesPerBlock + wid;
    const int nWaves = gridDim.x * wavesPerBlock;

    for (int base = waveId * 8; base < N; base += nWaves * 8) {
        if (base + 7 < N) {
            float d[8];
            #pragma unroll
            for (int r = 0; r < 8; ++r) {
                const f32x4 x = __builtin_nontemporal_load(
                    &X4[(size_t)(base + r) * 64 + lane]);
                d[r] = x.x * m4.x + x.y * m4.y + x.z * m4.z + x.w * m4.w;
            }

            // level 1: offset-32 swaps, merge row pairs
            float a01 = (lane < 32) ? d[0] : d[1];
            float b01 = (lane < 32) ? d[1] : d[0];
            a01 += __shfl_xor(b01, 32);
            float a23 = (lane < 32) ? d[2] : d[3];
            float b23 = (lane < 32) ? d[3] : d[2];
            a23 += __shfl_xor(b23, 32);
            float a45 = (lane < 32) ? d[4] : d[5];
            float b45 = (lane < 32) ? d[5] : d[4];
            a45 += __shfl_xor(b45, 32);
            float a67 = (lane < 32) ? d[6] : d[7];
            float b67 = (lane < 32) ? d[7] : d[6];
            a67 += __shfl_xor(b67, 32);

            // level 2: offset-16 swaps -> 16-lane groups
            float f0  = (lane & 16) ? a23 : a01;
            float f0p = (lane & 16) ? a01 : a23;
            f0 += __shfl_xor(f0p, 16);
            float f1  = (lane & 16) ? a67 : a45;
            float f1p = (lane & 16) ? a45 : a67;
            f1 += __shfl_xor(f1p, 16);

            // level 3: offset-8 swap -> 8-lane groups
            float g  = (lane & 8) ? f1 : f0;
            float gp = (lane & 8) ? f0 : f1;
            g += __shfl_xor(gp, 8);

            // intra-8 finish
            g += __shfl_xor(g, 4);
            g += __shfl_xor(g, 2);
            g += __shfl_xor(g, 1);

            if ((lane & 7) == 0) {
                const int h   = lane >> 3;
                const int idx = ((h & 1) << 2) | (((h >> 1) & 1) << 1) | (h >> 2);
                out[base + idx] = logC + kscale * g * g;
            }
        } else {
            // generic tail (unused when N % 8 == 0)
            for (int r = base; r < N; ++r) {
                const f32x4 x0 = X4[(size_t)r * 64 + lane];
                float d0 = x0.x * m4.x + x0.y * m4.y + x0.z * m4.z + x0.w * m4.w;
                #pragma unroll
                for (int o = 32; o > 0; o >>= 1) d0 += __shfl_xor(d0, o);
                if (lane == 0) out[r] = logC + kscale * d0 * d0;
            }
        }
    }
}

extern "C" void kernel_launch(void* const* d_in, const int* in_sizes, int n_in,
                              void* d_out, int out_size, void* d_ws, size_t ws_size,
                              hipStream_t stream) {
    const float* X     = (const float*)d_in[0];
    const float* mu    = (const float*)d_in[1];
    const float* kappa = (const float*)d_in[2];
    float* out = (float*)d_out;

    const int P = in_sizes[1];          // 256
    const int N = in_sizes[0] / P;      // 400000
    const int MAX_ITER = 50000;

    const int blocks = 2048;            // 8 blocks/CU, 32 waves/CU
    watson_fused_kernel<<<blocks, 256, 0, stream>>>(
        (const f32x4*)X, (const f32x4*)mu, kappa, out, N, P, MAX_ITER);
}